// Round 6
// baseline (270.507 us; speedup 1.0000x reference)
//
#include <hip/hip_runtime.h>

// ---------- types / helpers ----------
typedef __bf16 bf16x8 __attribute__((ext_vector_type(8)));
typedef float f32x4 __attribute__((ext_vector_type(4)));

struct alignas(16) US8 { unsigned short us[8]; };

static __device__ inline unsigned short f2bf(float f) {
  union { float f; unsigned u; } v; v.f = f;
  unsigned r = v.u + 0x7fffu + ((v.u >> 16) & 1u);   // RNE
  return (unsigned short)(r >> 16);
}
static __device__ inline float bf2f(unsigned short u) {
  union { unsigned u; float f; } t; t.u = (unsigned)u << 16; return t.f;
}

// B=8, N=4096, D=128.  32768 total rows.
#define NSEQ 4096
#define DIM 128
#define ROWS 32768
#define KH 2                      // cross-block key splits in attn

// log2(e)/sqrt(128): folded into q so S exits QK^T already in log2 domain
#define EXPC (1.4426950408889634f * 0.08838834764831845f)

// ---------- prep: weight transposes to bf16, wide (96 blocks) ----------
// blocks 0..63: wkvT (4 cols each); 64..95: wpT (4 cols each).
__global__ void prep_kernel(const float* __restrict__ Wkv, const float* __restrict__ Wp,
                            unsigned short* __restrict__ wkvT, unsigned short* __restrict__ wpT) {
  const int t = threadIdx.x;
  const int d = (t & 63) * 2;
  if (blockIdx.x < 64) {
    const int col = blockIdx.x * 4 + (t >> 6);
    unsigned short lo = f2bf(Wkv[d * 256 + col]);
    unsigned short hi = f2bf(Wkv[(d + 1) * 256 + col]);
    *reinterpret_cast<unsigned*>(&wkvT[col * 128 + d]) = (unsigned)lo | ((unsigned)hi << 16);
  } else {
    const int col = (blockIdx.x - 64) * 4 + (t >> 6);
    unsigned short lo = f2bf(Wp[d * 128 + col]);
    unsigned short hi = f2bf(Wp[(d + 1) * 128 + col]);
    *reinterpret_cast<unsigned*>(&wpT[col * 128 + d]) = (unsigned)lo | ((unsigned)hi << 16);
  }
}

// ---------- kv = x @ Wkv + bkv -> k_bf, vT_bf; blocks >= 256 do q scale+cast ----------
// GEMM part: 256 row-blocks (128 rows, all 256 output cols). Block 256 thr / 4 waves.
__global__ __launch_bounds__(256, 2) void kv_kernel(
    const float* __restrict__ x, const unsigned short* __restrict__ wkvT,
    const float* __restrict__ bkv, const float* __restrict__ q,
    unsigned short* __restrict__ kout, unsigned short* __restrict__ vtout,
    unsigned short* __restrict__ qo) {
  const int tid = threadIdx.x;
  if (blockIdx.x >= 256) {                  // q scale+cast tail blocks
    int i = ((blockIdx.x - 256) * 256 + tid) * 8;
    const float4* p = reinterpret_cast<const float4*>(q + i);
    float4 a = p[0], b = p[1];
    US8 o;
    o.us[0]=f2bf(a.x*EXPC); o.us[1]=f2bf(a.y*EXPC); o.us[2]=f2bf(a.z*EXPC); o.us[3]=f2bf(a.w*EXPC);
    o.us[4]=f2bf(b.x*EXPC); o.us[5]=f2bf(b.y*EXPC); o.us[6]=f2bf(b.z*EXPC); o.us[7]=f2bf(b.w*EXPC);
    *reinterpret_cast<US8*>(qo + i) = o;
    return;
  }
  __shared__ __align__(16) unsigned short WT[256 * 136];   // [col][d] stride 136 (69.6 KB)
  const int wv = tid >> 6, lane = tid & 63, l16 = lane & 15, quad = lane >> 4;
  const int row0 = blockIdx.x * 128;

  for (int p = 0; p < 16; ++p) {            // 4096 US8 chunks, b128 both sides
    int c = p * 256 + tid;
    int col = c >> 4, c16 = c & 15;
    *reinterpret_cast<US8*>(&WT[col * 136 + c16 * 8]) =
        *reinterpret_cast<const US8*>(wkvT + col * 128 + c16 * 8);
  }
  __syncthreads();

  // A-frags (both row-groups) once; 128 acc regs for all 256 cols
  bf16x8 afrag[2][4];
  for (int rg = 0; rg < 2; ++rg) {
    const int arow = row0 + wv * 32 + rg * 16 + l16;
    for (int s = 0; s < 4; ++s) {
      const float4* xp = reinterpret_cast<const float4*>(x + (size_t)arow * DIM + s * 32 + quad * 8);
      float4 u0 = xp[0], u1 = xp[1];
      US8 af;
      af.us[0]=f2bf(u0.x); af.us[1]=f2bf(u0.y); af.us[2]=f2bf(u0.z); af.us[3]=f2bf(u0.w);
      af.us[4]=f2bf(u1.x); af.us[5]=f2bf(u1.y); af.us[6]=f2bf(u1.z); af.us[7]=f2bf(u1.w);
      afrag[rg][s] = __builtin_bit_cast(bf16x8, af);
    }
  }
  f32x4 acc[2][16];
  for (int rg = 0; rg < 2; ++rg)
    for (int g = 0; g < 16; ++g) acc[rg][g] = f32x4{0.f, 0.f, 0.f, 0.f};
  for (int s = 0; s < 4; ++s)
    for (int g = 0; g < 16; ++g) {
      bf16x8 bfr = *reinterpret_cast<const bf16x8*>(&WT[(g * 16 + l16) * 136 + s * 32 + quad * 8]);
      acc[0][g] = __builtin_amdgcn_mfma_f32_16x16x32_bf16(afrag[0][s], bfr, acc[0][g], 0, 0, 0);
      acc[1][g] = __builtin_amdgcn_mfma_f32_16x16x32_bf16(afrag[1][s], bfr, acc[1][g], 0, 0, 0);
    }

  // k half: direct stores
  for (int rg = 0; rg < 2; ++rg)
    for (int g = 0; g < 8; ++g) {
      float bias = bkv[g * 16 + l16];
      for (int r = 0; r < 4; ++r) {
        int orow = row0 + wv * 32 + rg * 16 + quad * 4 + r;   // C/D: row=quad*4+r, col=l16
        kout[(size_t)orow * DIM + g * 16 + l16] = f2bf(acc[rg][g][r] + bias);
      }
    }
  // v half: transpose through LDS (reuse WT), then b128 copies out
  __syncthreads();
  unsigned short* LDSt = WT;                // [d][n_local] stride 136
  for (int rg = 0; rg < 2; ++rg)
    for (int g = 0; g < 8; ++g) {
      float bias = bkv[128 + g * 16 + l16];
      for (int r = 0; r < 4; ++r)
        LDSt[(g * 16 + l16) * 136 + wv * 32 + rg * 16 + quad * 4 + r] = f2bf(acc[rg][g + 8][r] + bias);
    }
  __syncthreads();
  const int bb = row0 >> 12, n0 = row0 & (NSEQ - 1);
  unsigned short* vb = vtout + (size_t)bb * NSEQ * DIM;
  for (int p = 0; p < 8; ++p) {             // 2048 chunks: 128 d x 16
    int c = p * 256 + tid;
    int d = c >> 4, c8 = c & 15;
    *reinterpret_cast<US8*>(vb + (size_t)d * NSEQ + n0 + c8 * 8) =
        *reinterpret_cast<const US8*>(&LDSt[d * 136 + c8 * 8]);
  }
}

// ---------- flash attention partials: Q:=k, K:=q_hat, V:=v -> bf16 O / fp32 l partials ----------
// grid 512 = 8 batches (blockIdx&7 -> XCD pin) x 32 q-tiles (128 rows) x 2 key-splits.
// Block 256 thr = 4 q-waves x 32 rows sharing one 64-key K/V^T tile. LDS 54.3 KB -> 2 blocks/CU.
// P rows stored permuted (row' = r*8 + rg*4 + quad): write banks all-distinct (R5's 9.4e6
// conflicts were 4-way P-writes). Next K/V tile prefetched into regs during compute.
__global__ __launch_bounds__(256, 2) void attn_kernel(
    const unsigned short* __restrict__ kbuf, const unsigned short* __restrict__ qbuf,
    const unsigned short* __restrict__ vtbuf,
    unsigned short* __restrict__ opart, float* __restrict__ lpart) {
  // shorts: Ksh 64x136 = 8704 | VTsh 128x72 = 9216 | Psh 4x32x72 = 9216
  __shared__ __align__(16) unsigned short SH[27136];   // 54272 B
  const int tid = threadIdx.x;
  const int wv = tid >> 6, lane = tid & 63, l16 = lane & 15, quad = lane >> 4;
  const int b = blockIdx.x & 7;
  const int t = blockIdx.x >> 3;
  const int q0 = (t & 31) * 128;
  const int kh = t >> 5;
  const int key0 = kh * (NSEQ / KH);
  const unsigned short* kb = kbuf + (size_t)b * NSEQ * DIM;
  const unsigned short* qb = qbuf + (size_t)b * NSEQ * DIM;
  const unsigned short* vtb = vtbuf + (size_t)b * NSEQ * DIM;

  unsigned short* Ksh  = SH;                      // [m][d] stride 136
  unsigned short* VTsh = SH + 8704;               // [d][m] stride 72
  unsigned short* pp   = SH + 17920 + wv * 2304;  // per-wave P, permuted rows, stride 72

  // A-frags: this wave's 32 "query" rows of k
  bf16x8 afrag[2][4];
  for (int rg = 0; rg < 2; ++rg) {
    const int arow = q0 + wv * 32 + rg * 16 + l16;
    for (int s = 0; s < 4; ++s)
      afrag[rg][s] = __builtin_bit_cast(bf16x8,
          *reinterpret_cast<const US8*>(kb + (size_t)arow * DIM + s * 32 + quad * 8));
  }

  f32x4 Oacc[2][8];
  for (int rg = 0; rg < 2; ++rg)
    for (int g = 0; g < 8; ++g) Oacc[rg][g] = f32x4{0.f, 0.f, 0.f, 0.f};
  float lsum[2][4];
  for (int rg = 0; rg < 2; ++rg)
    for (int r = 0; r < 4; ++r) lsum[rg][r] = 0.f;

  // staging chunk coords (fixed per thread)
  const int krow = tid >> 4, kc16 = tid & 15;     // K: 256 thr cover 1st 256 of 1024 chunks (p adds)
  const int vd = tid >> 3, vc8 = tid & 7;

  US8 kreg[4], vreg[4];
  {
    const int m0 = key0;
    for (int p = 0; p < 4; ++p)
      kreg[p] = *reinterpret_cast<const US8*>(qb + (size_t)(m0 + p * 16 + krow) * DIM + kc16 * 8);
    for (int p = 0; p < 4; ++p)
      vreg[p] = *reinterpret_cast<const US8*>(vtb + (size_t)(p * 32 + vd) * NSEQ + m0 + vc8 * 8);
  }

  const int ITERS = NSEQ / KH / 64;
  for (int it = 0; it < ITERS; ++it) {
    __syncthreads();                       // prior iter's reads done before overwrite
    for (int p = 0; p < 4; ++p)
      *reinterpret_cast<US8*>(&Ksh[(p * 16 + krow) * 136 + kc16 * 8]) = kreg[p];
    for (int p = 0; p < 4; ++p)
      *reinterpret_cast<US8*>(&VTsh[(p * 32 + vd) * 72 + vc8 * 8]) = vreg[p];
    __syncthreads();

    // prefetch next tile into regs (completes during compute)
    {
      const int mn = key0 + ((it + 1 < ITERS) ? (it + 1) * 64 : it * 64);
      for (int p = 0; p < 4; ++p)
        kreg[p] = *reinterpret_cast<const US8*>(qb + (size_t)(mn + p * 16 + krow) * DIM + kc16 * 8);
      for (int p = 0; p < 4; ++p)
        vreg[p] = *reinterpret_cast<const US8*>(vtb + (size_t)(p * 32 + vd) * NSEQ + mn + vc8 * 8);
    }

    // S[32 n][64 m]: each B-frag read feeds both row-groups
    f32x4 S[2][4];
    for (int rg = 0; rg < 2; ++rg)
      for (int g = 0; g < 4; ++g) S[rg][g] = f32x4{0.f, 0.f, 0.f, 0.f};
    for (int s = 0; s < 4; ++s)
      for (int g = 0; g < 4; ++g) {
        bf16x8 bfr = *reinterpret_cast<const bf16x8*>(&Ksh[(g * 16 + l16) * 136 + s * 32 + quad * 8]);
        S[0][g] = __builtin_amdgcn_mfma_f32_16x16x32_bf16(afrag[0][s], bfr, S[0][g], 0, 0, 0);
        S[1][g] = __builtin_amdgcn_mfma_f32_16x16x32_bf16(afrag[1][s], bfr, S[1][g], 0, 0, 0);
      }

    // P = exp2(S) (q pre-scaled), bf16-truncated; rows permuted: row' = r*8 + rg*4 + quad
    for (int rg = 0; rg < 2; ++rg)
      for (int g = 0; g < 4; ++g)
        for (int r = 0; r < 4; ++r) {
          float pv = exp2f(S[rg][g][r]);
          unsigned u = __builtin_bit_cast(unsigned, pv) & 0xffff0000u;
          lsum[rg][r] += __builtin_bit_cast(float, u);
          pp[(r * 8 + rg * 4 + quad) * 72 + g * 16 + l16] = (unsigned short)(u >> 16);
        }

    asm volatile("s_waitcnt lgkmcnt(0)" ::: "memory");  // wave-private P write->read

    // O += P @ V  (pa reads undo the row permutation: l16 -> (l16&3)*8 + rg*4 + (l16>>2))
    for (int s2 = 0; s2 < 2; ++s2) {
      bf16x8 pa0 = *reinterpret_cast<const bf16x8*>(&pp[((l16 & 3) * 8 + (l16 >> 2)) * 72 + s2 * 32 + quad * 8]);
      bf16x8 pa1 = *reinterpret_cast<const bf16x8*>(&pp[((l16 & 3) * 8 + 4 + (l16 >> 2)) * 72 + s2 * 32 + quad * 8]);
      for (int g = 0; g < 8; ++g) {
        bf16x8 vfr = *reinterpret_cast<const bf16x8*>(&VTsh[(g * 16 + l16) * 72 + s2 * 32 + quad * 8]);
        Oacc[0][g] = __builtin_amdgcn_mfma_f32_16x16x32_bf16(pa0, vfr, Oacc[0][g], 0, 0, 0);
        Oacc[1][g] = __builtin_amdgcn_mfma_f32_16x16x32_bf16(pa1, vfr, Oacc[1][g], 0, 0, 0);
      }
    }
  }

  // l row-sums: reduce across the 16 l16 lanes (quad preserved by masks<16)
  for (int rg = 0; rg < 2; ++rg)
    for (int r = 0; r < 4; ++r) {
      float v = lsum[rg][r];
      for (int m = 1; m < 16; m <<= 1) v += __shfl_xor(v, m);
      lsum[rg][r] = v;
    }
  if (l16 == 0) {
    float* lp = lpart + (size_t)kh * ROWS + (size_t)b * NSEQ + q0 + wv * 32;
    for (int rg = 0; rg < 2; ++rg)
      for (int r = 0; r < 4; ++r) lp[rg * 16 + quad * 4 + r] = lsum[rg][r];
  }
  unsigned short* ob = opart + (size_t)kh * ROWS * DIM + ((size_t)b * NSEQ + q0 + wv * 32) * DIM;
  for (int rg = 0; rg < 2; ++rg)
    for (int g = 0; g < 8; ++g)
      for (int r = 0; r < 4; ++r)
        ob[(rg * 16 + quad * 4 + r) * DIM + g * 16 + l16] = f2bf(Oacc[rg][g][r]);
}

// ---------- combine bf16 partials, normalize, out = o @ Wp + bp (fp32 out) ----------
// grid 256, block 256 / 4 waves; wave: 32 rows.
__global__ __launch_bounds__(256, 2) void combine_proj_kernel(
    const unsigned short* __restrict__ opart, const float* __restrict__ lpart,
    const unsigned short* __restrict__ wpT, const float* __restrict__ bp,
    float* __restrict__ out) {
  __shared__ __align__(16) unsigned short WT[128 * 136];
  const int tid = threadIdx.x;
  const int wv = tid >> 6, lane = tid & 63, l16 = lane & 15, quad = lane >> 4;
  const int row0 = blockIdx.x * 128;

  for (int p = 0; p < 8; ++p) {
    int c = p * 256 + tid;
    int col = c >> 4, c16 = c & 15;
    *reinterpret_cast<US8*>(&WT[col * 136 + c16 * 8]) =
        *reinterpret_cast<const US8*>(wpT + col * 128 + c16 * 8);
  }
  __syncthreads();

  f32x4 acc[2][8];
  for (int rg = 0; rg < 2; ++rg)
    for (int g = 0; g < 8; ++g) acc[rg][g] = f32x4{0.f, 0.f, 0.f, 0.f};
  for (int rg = 0; rg < 2; ++rg) {
    const int arow = row0 + wv * 32 + rg * 16 + l16;
    float linv = 1.f / (lpart[arow] + lpart[ROWS + arow]);
    for (int s = 0; s < 4; ++s) {
      const size_t base = (size_t)arow * DIM + s * 32 + quad * 8;
      US8 a0 = *reinterpret_cast<const US8*>(opart + base);
      US8 a1 = *reinterpret_cast<const US8*>(opart + (size_t)ROWS * DIM + base);
      US8 af;
      for (int j = 0; j < 8; ++j)
        af.us[j] = f2bf((bf2f(a0.us[j]) + bf2f(a1.us[j])) * linv);
      bf16x8 a = __builtin_bit_cast(bf16x8, af);
      for (int g = 0; g < 8; ++g) {
        bf16x8 bfr = *reinterpret_cast<const bf16x8*>(&WT[(g * 16 + l16) * 136 + s * 32 + quad * 8]);
        acc[rg][g] = __builtin_amdgcn_mfma_f32_16x16x32_bf16(a, bfr, acc[rg][g], 0, 0, 0);
      }
    }
  }
  for (int rg = 0; rg < 2; ++rg)
    for (int g = 0; g < 8; ++g) {
      float bias = bp[g * 16 + l16];
      for (int r = 0; r < 4; ++r) {
        int orow = row0 + wv * 32 + rg * 16 + quad * 4 + r;
        out[(size_t)orow * DIM + g * 16 + l16] = acc[rg][g][r] + bias;
      }
    }
}

extern "C" void kernel_launch(void* const* d_in, const int* in_sizes, int n_in,
                              void* d_out, int out_size, void* d_ws, size_t ws_size,
                              hipStream_t stream) {
  (void)in_sizes; (void)n_in; (void)out_size; (void)ws_size;
  const float* x   = (const float*)d_in[0];
  const float* qg  = (const float*)d_in[1];
  const float* Wkv = (const float*)d_in[2];
  const float* bkv = (const float*)d_in[3];
  const float* Wp  = (const float*)d_in[4];
  const float* bp  = (const float*)d_in[5];
  float* out = (float*)d_out;

  // workspace: 3x bf16 bufs 25.2MB | weights 96KB | l 256KB | O partials (bf16, KH=2) 16.8MB
  unsigned short* qbf  = (unsigned short*)d_ws;
  unsigned short* kbf  = qbf + (size_t)ROWS * DIM;
  unsigned short* vtbf = kbf + (size_t)ROWS * DIM;
  unsigned short* wkvT = vtbf + (size_t)ROWS * DIM;
  unsigned short* wpT  = wkvT + 256 * 128;
  float* lpart = (float*)(wpT + 128 * 128);
  unsigned short* opart = (unsigned short*)(lpart + (size_t)KH * ROWS);

  hipLaunchKernelGGL(prep_kernel, dim3(96), dim3(256), 0, stream, Wkv, Wp, wkvT, wpT);
  hipLaunchKernelGGL(kv_kernel, dim3(256 + 2048), dim3(256), 0, stream,
                     x, wkvT, bkv, qg, kbf, vtbf, qbf);
  hipLaunchKernelGGL(attn_kernel, dim3(8 * 32 * KH), dim3(256), 0, stream, kbf, qbf, vtbf, opart, lpart);
  hipLaunchKernelGGL(combine_proj_kernel, dim3(ROWS / 128), dim3(256), 0, stream, opart, lpart, wpT, bp, out);
}

// Round 7
// 196.351 us; speedup vs baseline: 1.3777x; 1.3777x over previous
//
#include <hip/hip_runtime.h>

// ---------- types / helpers ----------
typedef __bf16 bf16x8 __attribute__((ext_vector_type(8)));
typedef float f32x4 __attribute__((ext_vector_type(4)));

struct alignas(16) US8 { unsigned short us[8]; };

static __device__ inline unsigned short f2bf(float f) {
  union { float f; unsigned u; } v; v.f = f;
  unsigned r = v.u + 0x7fffu + ((v.u >> 16) & 1u);   // RNE
  return (unsigned short)(r >> 16);
}

// B=8, N=4096, D=128.  32768 total rows.
#define NSEQ 4096
#define DIM 128
#define ROWS 32768
#define KH 2                      // cross-block key splits in attn

// log2(e)/sqrt(128): folded into q so S exits QK^T already in log2 domain
#define EXPC (1.4426950408889634f * 0.08838834764831845f)

// ---------- prep: weight transposes to bf16, wide (96 blocks) ----------
__global__ void prep_kernel(const float* __restrict__ Wkv, const float* __restrict__ Wp,
                            unsigned short* __restrict__ wkvT, unsigned short* __restrict__ wpT) {
  const int t = threadIdx.x;
  const int d = (t & 63) * 2;
  if (blockIdx.x < 64) {
    const int col = blockIdx.x * 4 + (t >> 6);
    unsigned short lo = f2bf(Wkv[d * 256 + col]);
    unsigned short hi = f2bf(Wkv[(d + 1) * 256 + col]);
    *reinterpret_cast<unsigned*>(&wkvT[col * 128 + d]) = (unsigned)lo | ((unsigned)hi << 16);
  } else {
    const int col = (blockIdx.x - 64) * 4 + (t >> 6);
    unsigned short lo = f2bf(Wp[d * 128 + col]);
    unsigned short hi = f2bf(Wp[(d + 1) * 128 + col]);
    *reinterpret_cast<unsigned*>(&wpT[col * 128 + d]) = (unsigned)lo | ((unsigned)hi << 16);
  }
}

// ---------- kv = x @ Wkv + bkv -> k_bf, vT_bf; blocks >= 256 do q scale+cast ----------
// GEMM part: 256 row-blocks (128 rows, all 256 output cols). Block 256 thr / 4 waves.
__global__ __launch_bounds__(256, 2) void kv_kernel(
    const float* __restrict__ x, const unsigned short* __restrict__ wkvT,
    const float* __restrict__ bkv, const float* __restrict__ q,
    unsigned short* __restrict__ kout, unsigned short* __restrict__ vtout,
    unsigned short* __restrict__ qo) {
  const int tid = threadIdx.x;
  if (blockIdx.x >= 256) {                  // q scale+cast tail blocks
    int i = ((blockIdx.x - 256) * 256 + tid) * 8;
    const float4* p = reinterpret_cast<const float4*>(q + i);
    float4 a = p[0], b = p[1];
    US8 o;
    o.us[0]=f2bf(a.x*EXPC); o.us[1]=f2bf(a.y*EXPC); o.us[2]=f2bf(a.z*EXPC); o.us[3]=f2bf(a.w*EXPC);
    o.us[4]=f2bf(b.x*EXPC); o.us[5]=f2bf(b.y*EXPC); o.us[6]=f2bf(b.z*EXPC); o.us[7]=f2bf(b.w*EXPC);
    *reinterpret_cast<US8*>(qo + i) = o;
    return;
  }
  __shared__ __align__(16) unsigned short WT[256 * 136];   // [col][d] stride 136 (69.6 KB)
  const int wv = tid >> 6, lane = tid & 63, l16 = lane & 15, quad = lane >> 4;
  const int row0 = blockIdx.x * 128;

  for (int p = 0; p < 16; ++p) {            // 4096 US8 chunks, b128 both sides
    int c = p * 256 + tid;
    int col = c >> 4, c16 = c & 15;
    *reinterpret_cast<US8*>(&WT[col * 136 + c16 * 8]) =
        *reinterpret_cast<const US8*>(wkvT + col * 128 + c16 * 8);
  }
  __syncthreads();

  bf16x8 afrag[2][4];
  for (int rg = 0; rg < 2; ++rg) {
    const int arow = row0 + wv * 32 + rg * 16 + l16;
    for (int s = 0; s < 4; ++s) {
      const float4* xp = reinterpret_cast<const float4*>(x + (size_t)arow * DIM + s * 32 + quad * 8);
      float4 u0 = xp[0], u1 = xp[1];
      US8 af;
      af.us[0]=f2bf(u0.x); af.us[1]=f2bf(u0.y); af.us[2]=f2bf(u0.z); af.us[3]=f2bf(u0.w);
      af.us[4]=f2bf(u1.x); af.us[5]=f2bf(u1.y); af.us[6]=f2bf(u1.z); af.us[7]=f2bf(u1.w);
      afrag[rg][s] = __builtin_bit_cast(bf16x8, af);
    }
  }
  f32x4 acc[2][16];
  for (int rg = 0; rg < 2; ++rg)
    for (int g = 0; g < 16; ++g) acc[rg][g] = f32x4{0.f, 0.f, 0.f, 0.f};
  for (int s = 0; s < 4; ++s)
    for (int g = 0; g < 16; ++g) {
      bf16x8 bfr = *reinterpret_cast<const bf16x8*>(&WT[(g * 16 + l16) * 136 + s * 32 + quad * 8]);
      acc[0][g] = __builtin_amdgcn_mfma_f32_16x16x32_bf16(afrag[0][s], bfr, acc[0][g], 0, 0, 0);
      acc[1][g] = __builtin_amdgcn_mfma_f32_16x16x32_bf16(afrag[1][s], bfr, acc[1][g], 0, 0, 0);
    }

  // k half: direct stores
  for (int rg = 0; rg < 2; ++rg)
    for (int g = 0; g < 8; ++g) {
      float bias = bkv[g * 16 + l16];
      for (int r = 0; r < 4; ++r) {
        int orow = row0 + wv * 32 + rg * 16 + quad * 4 + r;   // C/D: row=quad*4+r, col=l16
        kout[(size_t)orow * DIM + g * 16 + l16] = f2bf(acc[rg][g][r] + bias);
      }
    }
  // v half: transpose through LDS (reuse WT), then b128 copies out
  __syncthreads();
  unsigned short* LDSt = WT;                // [d][n_local] stride 136
  for (int rg = 0; rg < 2; ++rg)
    for (int g = 0; g < 8; ++g) {
      float bias = bkv[128 + g * 16 + l16];
      for (int r = 0; r < 4; ++r)
        LDSt[(g * 16 + l16) * 136 + wv * 32 + rg * 16 + quad * 4 + r] = f2bf(acc[rg][g + 8][r] + bias);
    }
  __syncthreads();
  const int bb = row0 >> 12, n0 = row0 & (NSEQ - 1);
  unsigned short* vb = vtout + (size_t)bb * NSEQ * DIM;
  for (int p = 0; p < 8; ++p) {             // 2048 chunks: 128 d x 16
    int c = p * 256 + tid;
    int d = c >> 4, c8 = c & 15;
    *reinterpret_cast<US8*>(vb + (size_t)d * NSEQ + n0 + c8 * 8) =
        *reinterpret_cast<const US8*>(&LDSt[d * 136 + c8 * 8]);
  }
}

// ---------- flash attention partials: Q:=k, K:=q_hat, V:=v -> fp32 O/l partials ----------
// grid 512 = 8 batches (blockIdx&7 -> XCD pin) x 32 q-tiles (128 rows) x 2 key-splits.
// Block 256 thr = 4 q-waves x 32 rows sharing one 64-key K/V^T tile. LDS 54.3 KB -> 2 blocks/CU.
// P stored with XOR column swizzle (granule G = g ^ quad, 16-short granules): write banks
// tile all 32 (R5's 9.4e6 conflicts were the 16-bank/2-addr P-writes); pa-read bank-quads
// stay uniform (enumerated). fp32 O-partial dword stores (R6's bf16 short-scatter caused
// 11x HBM write amplification: WRITE_SIZE 181 MB vs 33 MB).
__global__ __launch_bounds__(256, 2) void attn_kernel(
    const unsigned short* __restrict__ kbuf, const unsigned short* __restrict__ qbuf,
    const unsigned short* __restrict__ vtbuf,
    float* __restrict__ opart, float* __restrict__ lpart) {
  // shorts: Ksh 64x136 = 8704 | VTsh 128x72 = 9216 | Psh 4x32x72 = 9216
  __shared__ __align__(16) unsigned short SH[27136];   // 54272 B
  const int tid = threadIdx.x;
  const int wv = tid >> 6, lane = tid & 63, l16 = lane & 15, quad = lane >> 4;
  const int b = blockIdx.x & 7;
  const int t = blockIdx.x >> 3;
  const int q0 = (t & 31) * 128;
  const int kh = t >> 5;
  const int key0 = kh * (NSEQ / KH);
  const unsigned short* kb = kbuf + (size_t)b * NSEQ * DIM;
  const unsigned short* qb = qbuf + (size_t)b * NSEQ * DIM;
  const unsigned short* vtb = vtbuf + (size_t)b * NSEQ * DIM;

  unsigned short* Ksh  = SH;                      // [m][d] stride 136
  unsigned short* VTsh = SH + 8704;               // [d][m] stride 72
  unsigned short* pp   = SH + 17920 + wv * 2304;  // per-wave P [n][m] stride 72, col-swizzled

  // A-frags: this wave's 32 "query" rows of k
  bf16x8 afrag[2][4];
  for (int rg = 0; rg < 2; ++rg) {
    const int arow = q0 + wv * 32 + rg * 16 + l16;
    for (int s = 0; s < 4; ++s)
      afrag[rg][s] = __builtin_bit_cast(bf16x8,
          *reinterpret_cast<const US8*>(kb + (size_t)arow * DIM + s * 32 + quad * 8));
  }

  f32x4 Oacc[2][8];
  for (int rg = 0; rg < 2; ++rg)
    for (int g = 0; g < 8; ++g) Oacc[rg][g] = f32x4{0.f, 0.f, 0.f, 0.f};
  float lsum[2][4];
  for (int rg = 0; rg < 2; ++rg)
    for (int r = 0; r < 4; ++r) lsum[rg][r] = 0.f;

  for (int it = 0; it < NSEQ / KH / 64; ++it) {
    const int m0 = key0 + it * 64;
    __syncthreads();                       // prior iter's reads done before overwrite
    for (int p = 0; p < 4; ++p) {          // stage K tile: 1024 b128 chunks
      int c = p * 256 + tid;
      int row = c >> 4, c16 = c & 15;
      *reinterpret_cast<US8*>(&Ksh[row * 136 + c16 * 8]) =
          *reinterpret_cast<const US8*>(qb + (size_t)(m0 + row) * DIM + c16 * 8);
    }
    for (int p = 0; p < 4; ++p) {          // stage V^T tile: b128 chunks
      int c = p * 256 + tid;
      int d = c >> 3, c8 = c & 7;
      *reinterpret_cast<US8*>(&VTsh[d * 72 + c8 * 8]) =
          *reinterpret_cast<const US8*>(vtb + (size_t)d * NSEQ + m0 + c8 * 8);
    }
    __syncthreads();

    // S[32 n][64 m]: each B-frag read feeds both row-groups
    f32x4 S[2][4];
    for (int rg = 0; rg < 2; ++rg)
      for (int g = 0; g < 4; ++g) S[rg][g] = f32x4{0.f, 0.f, 0.f, 0.f};
    for (int s = 0; s < 4; ++s)
      for (int g = 0; g < 4; ++g) {
        bf16x8 bfr = *reinterpret_cast<const bf16x8*>(&Ksh[(g * 16 + l16) * 136 + s * 32 + quad * 8]);
        S[0][g] = __builtin_amdgcn_mfma_f32_16x16x32_bf16(afrag[0][s], bfr, S[0][g], 0, 0, 0);
        S[1][g] = __builtin_amdgcn_mfma_f32_16x16x32_bf16(afrag[1][s], bfr, S[1][g], 0, 0, 0);
      }

    // P = exp2(S) (q pre-scaled), bf16-truncated; col granule swizzled: G = g ^ quad
    for (int rg = 0; rg < 2; ++rg)
      for (int g = 0; g < 4; ++g)
        for (int r = 0; r < 4; ++r) {
          float pv = exp2f(S[rg][g][r]);
          unsigned u = __builtin_bit_cast(unsigned, pv) & 0xffff0000u;
          lsum[rg][r] += __builtin_bit_cast(float, u);
          pp[(rg * 16 + quad * 4 + r) * 72 + ((g ^ quad) * 16) + l16] = (unsigned short)(u >> 16);
        }

    asm volatile("s_waitcnt lgkmcnt(0)" ::: "memory");  // wave-private P write->read

    // O += P @ V  (pa reads undo the swizzle: G = (s2*2 + (quad>>1)) ^ (l16>>2))
    for (int s2 = 0; s2 < 2; ++s2) {
      const int G = ((s2 * 2 + (quad >> 1)) ^ (l16 >> 2)) * 16 + (quad & 1) * 8;
      bf16x8 pa0 = *reinterpret_cast<const bf16x8*>(&pp[l16 * 72 + G]);
      bf16x8 pa1 = *reinterpret_cast<const bf16x8*>(&pp[(16 + l16) * 72 + G]);
      for (int g = 0; g < 8; ++g) {
        bf16x8 vfr = *reinterpret_cast<const bf16x8*>(&VTsh[(g * 16 + l16) * 72 + s2 * 32 + quad * 8]);
        Oacc[0][g] = __builtin_amdgcn_mfma_f32_16x16x32_bf16(pa0, vfr, Oacc[0][g], 0, 0, 0);
        Oacc[1][g] = __builtin_amdgcn_mfma_f32_16x16x32_bf16(pa1, vfr, Oacc[1][g], 0, 0, 0);
      }
    }
  }

  // l row-sums: reduce across the 16 l16 lanes (quad preserved by masks<16)
  for (int rg = 0; rg < 2; ++rg)
    for (int r = 0; r < 4; ++r) {
      float v = lsum[rg][r];
      for (int m = 1; m < 16; m <<= 1) v += __shfl_xor(v, m);
      lsum[rg][r] = v;
    }
  if (l16 == 0) {
    float* lp = lpart + (size_t)kh * ROWS + (size_t)b * NSEQ + q0 + wv * 32;
    for (int rg = 0; rg < 2; ++rg)
      for (int r = 0; r < 4; ++r) lp[rg * 16 + quad * 4 + r] = lsum[rg][r];
  }
  float* ob = opart + (size_t)kh * ROWS * DIM + ((size_t)b * NSEQ + q0 + wv * 32) * DIM;
  for (int rg = 0; rg < 2; ++rg)
    for (int g = 0; g < 8; ++g)
      for (int r = 0; r < 4; ++r)
        ob[(rg * 16 + quad * 4 + r) * DIM + g * 16 + l16] = Oacc[rg][g][r];
}

// ---------- combine fp32 partials, normalize, out = o @ Wp + bp (fp32 out) ----------
// grid 256, block 256 / 4 waves; wave: 32 rows.
__global__ __launch_bounds__(256, 2) void combine_proj_kernel(
    const float* __restrict__ opart, const float* __restrict__ lpart,
    const unsigned short* __restrict__ wpT, const float* __restrict__ bp,
    float* __restrict__ out) {
  __shared__ __align__(16) unsigned short WT[128 * 136];
  const int tid = threadIdx.x;
  const int wv = tid >> 6, lane = tid & 63, l16 = lane & 15, quad = lane >> 4;
  const int row0 = blockIdx.x * 128;

  for (int p = 0; p < 8; ++p) {
    int c = p * 256 + tid;
    int col = c >> 4, c16 = c & 15;
    *reinterpret_cast<US8*>(&WT[col * 136 + c16 * 8]) =
        *reinterpret_cast<const US8*>(wpT + col * 128 + c16 * 8);
  }
  __syncthreads();

  f32x4 acc[2][8];
  for (int rg = 0; rg < 2; ++rg)
    for (int g = 0; g < 8; ++g) acc[rg][g] = f32x4{0.f, 0.f, 0.f, 0.f};
  for (int rg = 0; rg < 2; ++rg) {
    const int arow = row0 + wv * 32 + rg * 16 + l16;
    float linv = 1.f / (lpart[arow] + lpart[ROWS + arow]);
    for (int s = 0; s < 4; ++s) {
      const size_t base = (size_t)arow * DIM + s * 32 + quad * 8;
      float4 s0 = *reinterpret_cast<const float4*>(opart + base);
      float4 s1 = *reinterpret_cast<const float4*>(opart + base + 4);
      float4 u0 = *reinterpret_cast<const float4*>(opart + (size_t)ROWS * DIM + base);
      float4 u1 = *reinterpret_cast<const float4*>(opart + (size_t)ROWS * DIM + base + 4);
      US8 af;
      af.us[0]=f2bf((s0.x+u0.x)*linv); af.us[1]=f2bf((s0.y+u0.y)*linv);
      af.us[2]=f2bf((s0.z+u0.z)*linv); af.us[3]=f2bf((s0.w+u0.w)*linv);
      af.us[4]=f2bf((s1.x+u1.x)*linv); af.us[5]=f2bf((s1.y+u1.y)*linv);
      af.us[6]=f2bf((s1.z+u1.z)*linv); af.us[7]=f2bf((s1.w+u1.w)*linv);
      bf16x8 a = __builtin_bit_cast(bf16x8, af);
      for (int g = 0; g < 8; ++g) {
        bf16x8 bfr = *reinterpret_cast<const bf16x8*>(&WT[(g * 16 + l16) * 136 + s * 32 + quad * 8]);
        acc[rg][g] = __builtin_amdgcn_mfma_f32_16x16x32_bf16(a, bfr, acc[rg][g], 0, 0, 0);
      }
    }
  }
  for (int rg = 0; rg < 2; ++rg)
    for (int g = 0; g < 8; ++g) {
      float bias = bp[g * 16 + l16];
      for (int r = 0; r < 4; ++r) {
        int orow = row0 + wv * 32 + rg * 16 + quad * 4 + r;
        out[(size_t)orow * DIM + g * 16 + l16] = acc[rg][g][r] + bias;
      }
    }
}

extern "C" void kernel_launch(void* const* d_in, const int* in_sizes, int n_in,
                              void* d_out, int out_size, void* d_ws, size_t ws_size,
                              hipStream_t stream) {
  (void)in_sizes; (void)n_in; (void)out_size; (void)ws_size;
  const float* x   = (const float*)d_in[0];
  const float* qg  = (const float*)d_in[1];
  const float* Wkv = (const float*)d_in[2];
  const float* bkv = (const float*)d_in[3];
  const float* Wp  = (const float*)d_in[4];
  const float* bp  = (const float*)d_in[5];
  float* out = (float*)d_out;

  // workspace: 3x bf16 bufs 25.2MB | weights 96KB | l 256KB | O partials (fp32, KH=2) 33.6MB
  unsigned short* qbf  = (unsigned short*)d_ws;
  unsigned short* kbf  = qbf + (size_t)ROWS * DIM;
  unsigned short* vtbf = kbf + (size_t)ROWS * DIM;
  unsigned short* wkvT = vtbf + (size_t)ROWS * DIM;
  unsigned short* wpT  = wkvT + 256 * 128;
  float* lpart = (float*)(wpT + 128 * 128);
  float* opart = lpart + (size_t)KH * ROWS;

  hipLaunchKernelGGL(prep_kernel, dim3(96), dim3(256), 0, stream, Wkv, Wp, wkvT, wpT);
  hipLaunchKernelGGL(kv_kernel, dim3(256 + 2048), dim3(256), 0, stream,
                     x, wkvT, bkv, qg, kbf, vtbf, qbf);
  hipLaunchKernelGGL(attn_kernel, dim3(8 * 32 * KH), dim3(256), 0, stream, kbf, qbf, vtbf, opart, lpart);
  hipLaunchKernelGGL(combine_proj_kernel, dim3(ROWS / 128), dim3(256), 0, stream, opart, lpart, wpT, bp, out);
}